// Round 2
// baseline (804.723 us; speedup 1.0000x reference)
//
#include <hip/hip_runtime.h>
#include <hip/hip_bf16.h>

typedef __bf16 bf16x8 __attribute__((ext_vector_type(8)));
typedef __bf16 bf16x4 __attribute__((ext_vector_type(4)));
typedef float  f32x16 __attribute__((ext_vector_type(16)));

#define BM 64            // batch rows per block (2 batch-tiles of 32)
#define S  520           // bf16 elems per LDS activation row (512 + 8)
#define SF 260           // f32 elems per LDS row for out staging (same 1040 B)
#define PANS 16384       // shorts per weight-panel buffer (32 KB), fixed stride

// ---------------- weight prepack ----------------
// A-operand = W^T for v_mfma_f32_32x32x16_bf16.
// A[m][k]: m = lane&31 (out-feature), k = (lane>>5)*8 + j.
// NEW unit order (panel-major so a K-step panel is contiguous):
//   unit = unitBase[w] + ((kt*(N/32) + mt)*2 + kcl)*64 + lane
// elem j = W[kt*32 + kcl*16 + (lane>>5)*8 + j][mt*32 + (lane&31)]
struct PrepParams {
    const float* src[9];
    int Kt[9];       // K/32
    int Mg[9];       // N/128 (col groups)
    int N[9];
    int blkEnd[9];
    int unitBase[9];
};

__global__ void __launch_bounds__(256)
prep_weights(PrepParams p, uint4* __restrict__ dst) {
    __shared__ float tile[32][128];
    int b = blockIdx.x;
    int w = 0;
    while (b >= p.blkEnd[w]) ++w;
    int local = b - ((w == 0) ? 0 : p.blkEnd[w - 1]);
    int mgc = p.Mg[w];
    int kt = local / mgc;
    int mg = local - kt * mgc;
    const float* src = p.src[w];
    int N = p.N[w];
    int Nmt = N >> 5;                // mtiles in this weight
    int t = threadIdx.x;

    int row0 = kt * 32, col0 = mg * 128;
#pragma unroll
    for (int i = 0; i < 4; ++i) {
        int e4 = t + i * 256;            // 1024 float4 in 32x128 tile
        int r = e4 >> 5;
        int c4 = e4 & 31;
        float4 v = *(const float4*)&src[(size_t)(row0 + r) * N + col0 + c4 * 4];
        *(float4*)&tile[r][c4 * 4] = v;
    }
    __syncthreads();

#pragma unroll
    for (int rep = 0; rep < 2; ++rep) {
        int ul = t + rep * 256;          // 512 units per block
        int lane = ul & 63;
        int kcl = (ul >> 6) & 1;
        int mtl = ul >> 7;               // 0..3
        int mt = mg * 4 + mtl;
        int gUnit = p.unitBase[w] + ((kt * Nmt + mt) * 2 + kcl) * 64 + lane;
        int lr = kcl * 16 + ((lane >> 5) << 3);
        int lc = mtl * 32 + (lane & 31);
        alignas(16) unsigned short u8[8];
#pragma unroll
        for (int j = 0; j < 8; ++j)
            u8[j] = __builtin_bit_cast(unsigned short, (__bf16)tile[lr + j][lc]);
        dst[gUnit] = *(const uint4*)u8;
    }
}

// ---------------- fused MLP ----------------
struct MlpParams {
    const float* X[3];
    const unsigned short* Wp[3];
    const float* B1[3];
    const float* B2[3];
    const float* B3[3];
    int dIn[3];
    int Nt[3];
    int rowOff[3];
    int blkStart[3];
};

__device__ __forceinline__ float sigmoidf(float z) {
    return __builtin_amdgcn_rcpf(
        1.0f + __builtin_amdgcn_exp2f(-1.442695040888963f * z));
}

// async global->LDS, 16B per lane, wave-uniform LDS base (+lane*16 in HW)
__device__ __forceinline__ void gload_lds16(const void* g, void* l) {
    __builtin_amdgcn_global_load_lds(
        (const __attribute__((address_space(1))) unsigned int*)g,
        (__attribute__((address_space(3))) unsigned int*)l, 16, 0, 0);
}

// Stage one weight panel (M*512 units of 16B) cooperatively: wave w issues M
// global_load_lds of 1KB each, LDS layout == global unit order (linear).
template <int M>
__device__ __forceinline__ void stageW(unsigned short* pan, int bufIdx,
                                       const uint4* src, int wave, int lane) {
    unsigned short* dst = pan + bufIdx * PANS + (wave * M) * 512;
    const uint4* s = src + (size_t)(wave * M) * 64 + lane;
#pragma unroll
    for (int i = 0; i < M; ++i)
        gload_lds16(s + i * 64, dst + i * 512);
}

// Weights-in-LDS layer. Wave = (bt, fg): bt = wave>>2 batch-tile (32 rows),
// fg = wave&3 feature-group (MTW mtiles of 32 feats). Per K-step (32 k):
// panel (all mtiles) is in LDS; double-buffered; the load for step k+1 flies
// under step k's MFMA. Last step stages NEXT layer's panel 0 (NEXTM>0).
// C/D: batchcol = lane&31, featrow = (reg&3)+8*(reg>>2)+4*(lane>>5).
template <int KSTEPS, int MTW, int NEXTM, bool TO_LDS>
__device__ __forceinline__ void layer(
    unsigned short* __restrict__ buf,       // activations [BM][S]
    unsigned short* __restrict__ pan,       // panel dbuf (2 x PANS shorts)
    const uint4* __restrict__ W,            // this layer, unit-ordered
    const uint4* __restrict__ Wnext,        // next layer (panel 0) or null
    const float* __restrict__ bias,
    int wave, int lane, int& cur)
{
    const int bt = wave >> 2;
    const int fg = wave & 3;
    const int half = lane >> 5;
    const int lr = lane & 31;

    f32x16 acc[MTW];
#pragma unroll
    for (int m = 0; m < MTW; ++m)
#pragma unroll
        for (int e = 0; e < 16; ++e)
            acc[m][e] = 0.0f;

    const unsigned short* bp = buf + (size_t)(bt * 32 + lr) * S + half * 8;

#pragma unroll
    for (int kc2 = 0; kc2 < KSTEPS; ++kc2) {
        if (kc2 + 1 < KSTEPS) {
            stageW<MTW>(pan, cur ^ 1,
                        W + (size_t)(kc2 + 1) * (MTW * 512), wave, lane);
        } else if constexpr (NEXTM > 0) {
            stageW<NEXTM>(pan, cur ^ 1, Wnext, wave, lane);
        }
        const unsigned short* pcur = pan + cur * PANS;
#pragma unroll
        for (int kcl = 0; kcl < 2; ++kcl) {
            bf16x8 b = *(const bf16x8*)(bp + (kc2 * 2 + kcl) * 16);
#pragma unroll
            for (int m = 0; m < MTW; ++m) {
                bf16x8 a = *(const bf16x8*)(
                    pcur + (((fg * MTW + m) * 2 + kcl) * 64 + lane) * 8);
                acc[m] = __builtin_amdgcn_mfma_f32_32x32x16_bf16(
                    a, b, acc[m], 0, 0, 0);
            }
        }
        __syncthreads();   // drains: my ds_reads done + staged loads landed
        cur ^= 1;
    }

    // epilogue: bias + sigmoid + write back (reads all drained by last barrier)
#pragma unroll
    for (int m = 0; m < MTW; ++m) {
        int mt = fg * MTW + m;
#pragma unroll
        for (int g = 0; g < 4; ++g) {
            int f0 = mt * 32 + g * 8 + half * 4;   // 4 consecutive features
            float4 bv = *(const float4*)(bias + f0);
            int r = bt * 32 + lr;
            float s0 = sigmoidf(acc[m][g * 4 + 0] + bv.x);
            float s1 = sigmoidf(acc[m][g * 4 + 1] + bv.y);
            float s2 = sigmoidf(acc[m][g * 4 + 2] + bv.z);
            float s3 = sigmoidf(acc[m][g * 4 + 3] + bv.w);
            if constexpr (TO_LDS) {
                bf16x4 h = {(__bf16)s0, (__bf16)s1, (__bf16)s2, (__bf16)s3};
                *(bf16x4*)(buf + (size_t)r * S + f0) = h;      // packed b64
            } else {
                float* fb = (float*)buf;
                *(float4*)(fb + (size_t)r * SF + f0) =
                    make_float4(s0, s1, s2, s3);               // b128
            }
        }
    }
}

__global__ void __launch_bounds__(512, 2)   // 1 block/CU (LDS 132 KB)
mlp_fused(MlpParams p, float* __restrict__ out) {
    extern __shared__ unsigned short buf[];
    unsigned short* pan = buf + BM * S;     // 2 x 32KB panel dbuf

    // bijective chunked XCD swizzle (m204): same-type blocks cluster per XCD
    int nwg = gridDim.x;
    int bid = blockIdx.x;
    int q = nwg >> 3, r8 = nwg & 7;
    int xcd = bid & 7, lid = bid >> 3;
    int b = (xcd < r8 ? xcd * (q + 1) : r8 * (q + 1) + (xcd - r8) * q) + lid;

    int t = (b >= p.blkStart[1]) + (b >= p.blkStart[2]);
    int blk = b - p.blkStart[t];
    int dIn = p.dIn[t];
    int Nt = p.Nt[t];
    int row0 = blk * BM;
    const float* X = p.X[t];
    const uint4* W1u = (const uint4*)p.Wp[t];
    const uint4* W2u = W1u + ((size_t)dIn * 512 >> 3);
    const uint4* W3u = W2u + ((size_t)512 * 512 >> 3);

    int tid = threadIdx.x;
    int wave = tid >> 6;
    int lane = tid & 63;
    int cur = 0;

    // L1 panel 0 latency hides under X staging
    stageW<4>(pan, 0, W1u, wave, lane);

    // ---- stage X (fp32 global -> bf16 LDS rows [batch][feat]) ----
    int d4 = dIn >> 2;               // float4 per row (16/32/64)
    int s4 = 31 - __clz(d4);
    int nf4 = BM * d4;
    for (int i = tid; i < nf4; i += 512) {
        int r = i >> s4;
        int c4 = i & (d4 - 1);
        int grow = row0 + r;
        float4 v = make_float4(0.f, 0.f, 0.f, 0.f);
        if (grow < Nt) v = ((const float4*)X)[(size_t)grow * d4 + c4];
        ushort4 u;
        u.x = __builtin_bit_cast(unsigned short, (__bf16)v.x);
        u.y = __builtin_bit_cast(unsigned short, (__bf16)v.y);
        u.z = __builtin_bit_cast(unsigned short, (__bf16)v.z);
        u.w = __builtin_bit_cast(unsigned short, (__bf16)v.w);
        *(ushort4*)(buf + r * S + c4 * 4) = u;
    }
    __syncthreads();                 // drains X stores + L1 panel 0 loads

    // L1: X -> H1 in place (KSTEPS = dIn/32); last step stages L2 panel 0
    if (t == 0)      layer<2, 4, 4, true>(buf, pan, W1u, W2u, p.B1[t], wave, lane, cur);
    else if (t == 1) layer<4, 4, 4, true>(buf, pan, W1u, W2u, p.B1[t], wave, lane, cur);
    else             layer<8, 4, 4, true>(buf, pan, W1u, W2u, p.B1[t], wave, lane, cur);
    __syncthreads();
    // L2: H1 -> H2 in place; last step stages L3 panel 0
    layer<16, 4, 2, true>(buf, pan, W2u, W3u, p.B2[t], wave, lane, cur);
    __syncthreads();
    // L3: H2 -> f32 staging (256 feats, MTW=2)
    layer<16, 2, 0, false>(buf, pan, W3u, nullptr, p.B3[t], wave, lane, cur);
    __syncthreads();

    // ---- coalesced output store: 64 rows x 256 f32, full 1KB rows ----
    const float* fb = (const float*)buf;
    float* gOut = out + (size_t)(p.rowOff[t] + row0) * 256;
    for (int i = tid; i < BM * 64; i += 512) {   // 4096 float4
        int r = i >> 6;
        int c4 = i & 63;
        if (row0 + r < Nt)
            *(float4*)(gOut + r * 256 + c4 * 4) =
                *(const float4*)(fb + r * SF + c4 * 4);
    }
}

// ---------------- launch ----------------
extern "C" void kernel_launch(void* const* d_in, const int* in_sizes, int n_in,
                              void* d_out, int out_size, void* d_ws, size_t ws_size,
                              hipStream_t stream) {
    const int IN0[3] = {64, 128, 256};
    const int CNT[3] = {100000, 80000, 60000};

    // ---- prepack weights into ws (bf16, panel-major A-fragment order) ----
    PrepParams pp;
    int blocks = 0, ubase = 0;
    for (int t = 0; t < 3; ++t) {
        int Ks[3] = {IN0[t], 512, 512};
        int Ns[3] = {512, 512, 256};
        for (int l = 0; l < 3; ++l) {
            int w = t * 3 + l;
            pp.src[w] = (const float*)d_in[4 + t * 6 + l * 2];
            pp.Kt[w] = Ks[l] >> 5;
            pp.Mg[w] = Ns[l] >> 7;
            pp.N[w] = Ns[l];
            pp.unitBase[w] = ubase;
            blocks += pp.Kt[w] * pp.Mg[w];
            pp.blkEnd[w] = blocks;
            ubase += (Ks[l] * Ns[l]) >> 3;
        }
    }
    prep_weights<<<dim3(blocks), dim3(256), 0, stream>>>(pp, (uint4*)d_ws);

    // ---- fused MLP ----
    MlpParams mp;
    int woff = 0, roff = 0, boff = 0;
    for (int t = 0; t < 3; ++t) {
        mp.X[t] = (const float*)d_in[t];
        mp.Wp[t] = (const unsigned short*)d_ws + woff;
        mp.B1[t] = (const float*)d_in[4 + t * 6 + 1];
        mp.B2[t] = (const float*)d_in[4 + t * 6 + 3];
        mp.B3[t] = (const float*)d_in[4 + t * 6 + 5];
        mp.dIn[t] = IN0[t];
        mp.Nt[t] = CNT[t];
        mp.rowOff[t] = roff;
        mp.blkStart[t] = boff;
        woff += IN0[t] * 512 + 512 * 512 + 512 * 256;
        roff += CNT[t];
        boff += (CNT[t] + BM - 1) / BM;
    }
    size_t lds = (size_t)(BM * S + 2 * PANS) * sizeof(unsigned short); // 132,096 B
    mlp_fused<<<dim3(boff), dim3(512), lds, stream>>>(mp, (float*)d_out);
}

// Round 3
// 707.809 us; speedup vs baseline: 1.1369x; 1.1369x over previous
//
#include <hip/hip_runtime.h>
#include <hip/hip_bf16.h>

typedef __bf16 bf16x8 __attribute__((ext_vector_type(8)));
typedef __bf16 bf16x4 __attribute__((ext_vector_type(4)));
typedef float  f32x16 __attribute__((ext_vector_type(16)));

#define MFMA __builtin_amdgcn_mfma_f32_32x32x16_bf16
#define BM 64            // batch rows per block (2 batch-tiles of 32)

// ---------------- weight prepack ----------------
// A-operand = W^T for v_mfma_f32_32x32x16_bf16.
// A[m][k]: m = lane&31 (out-feature), k = (lane>>5)*8 + j.
// Panel-major unit order: panel = 8 units (mtiles) x 16 k = 8 KB.
// For N=512: panel p = k16*2 + (mt>>3), ml = mt&7 (feature halves alternate).
// For N=256: panel p = k16, ml = mt.
// unit addr (uint4) = unitBase + (p*8 + ml)*64 + lane
// elem j = W[k16*16 + (lane>>5)*8 + j][mt*32 + (lane&31)]
struct PrepParams {
    const float* src[9];
    int Kt[9];       // K/32
    int Mg[9];       // N/128 (col groups)
    int N[9];
    int blkEnd[9];
    int unitBase[9];
};

__global__ void __launch_bounds__(256)
prep_weights(PrepParams p, uint4* __restrict__ dst) {
    __shared__ float tile[32][128];
    int b = blockIdx.x;
    int w = 0;
    while (b >= p.blkEnd[w]) ++w;
    int local = b - ((w == 0) ? 0 : p.blkEnd[w - 1]);
    int mgc = p.Mg[w];
    int kt = local / mgc;
    int mg = local - kt * mgc;
    const float* src = p.src[w];
    int N = p.N[w];
    int t = threadIdx.x;

    int row0 = kt * 32, col0 = mg * 128;
#pragma unroll
    for (int i = 0; i < 4; ++i) {
        int e4 = t + i * 256;            // 1024 float4 in 32x128 tile
        int r = e4 >> 5;
        int c4 = e4 & 31;
        float4 v = *(const float4*)&src[(size_t)(row0 + r) * N + col0 + c4 * 4];
        *(float4*)&tile[r][c4 * 4] = v;
    }
    __syncthreads();

#pragma unroll
    for (int rep = 0; rep < 2; ++rep) {
        int ul = t + rep * 256;          // 512 units per block
        int lane = ul & 63;
        int kcl = (ul >> 6) & 1;
        int mtl = ul >> 7;               // 0..3
        int mt = mg * 4 + mtl;
        int k16 = kt * 2 + kcl;
        int pidx = (N == 512) ? (k16 * 2 + (mt >> 3)) : k16;
        int ml = mt & 7;
        int gUnit = p.unitBase[w] + (pidx * 8 + ml) * 64 + lane;
        int lr = kcl * 16 + ((lane >> 5) << 3);
        int lc = mtl * 32 + (lane & 31);
        alignas(16) unsigned short u8[8];
#pragma unroll
        for (int j = 0; j < 8; ++j)
            u8[j] = __builtin_bit_cast(unsigned short, (__bf16)tile[lr + j][lc]);
        dst[gUnit] = *(const uint4*)u8;
    }
}

// ---------------- fused MLP ----------------
struct MlpParams {
    const float* X[3];
    const unsigned short* Wp[3];
    const float* B1[3];
    const float* B2[3];
    const float* B3[3];
    int dIn[3];
    int Nt[3];
    int rowOff[3];
    int blkStart[3];
};

__device__ __forceinline__ float sigmoidf(float z) {
    return __builtin_amdgcn_rcpf(
        1.0f + __builtin_amdgcn_exp2f(-1.442695040888963f * z));
}

// XOR-swizzle on byte offsets within the 64KB act buffer: rows are 1024 B;
// flip bits [8:4] with row&31 -> b-reads (32 lanes, same col, 32 rows) hit
// 32 distinct 16B slots. Bijective per row; preserves 16B granules.
__device__ __forceinline__ unsigned swz(unsigned o) {
    return o ^ (((o >> 10) & 31) << 4);
}

// async global->LDS, 16B per lane: per-lane global src, wave-uniform LDS base
__device__ __forceinline__ void gload_lds16(const void* g, void* l) {
    __builtin_amdgcn_global_load_lds(
        (const __attribute__((address_space(1))) unsigned int*)g,
        (__attribute__((address_space(3))) unsigned int*)l, 16, 0, 0);
}

// One pipeline half-step: compute panel in rc (8 units x 16k), prefetch the
// next panel into rn with counted vmcnt (loads stay in flight across the
// barriers; vmcnt(0) only at the very last panel of the type's stream).
// Wave (fg=wave) owns units fg*2+{0,1} x both batch-tiles: 4 ds_read feed
// 4 MFMAs (register-level operand reuse keeps the LDS pipe under the MFMA
// pipe). b-reads issued before the wait block to hide their lgkm latency
// (act is stable during a layer's steps).
__device__ __forceinline__ void halfstep(
    const char* act, unsigned bo0, unsigned bo1, int k16,
    const unsigned short* rc, unsigned short* rn,
    const uint4*& wsrc, bool pf, int wave, int lane,
    f32x16& a00, f32x16& a01, f32x16& a10, f32x16& a11)
{
    unsigned o0 = bo0 + (unsigned)k16 * 32;
    unsigned o1 = bo1 + (unsigned)k16 * 32;
    bf16x8 b0 = *(const bf16x8*)(act + swz(o0));
    bf16x8 b1 = *(const bf16x8*)(act + swz(o1));
    if (pf) {
        gload_lds16(wsrc + wave * 128 + lane,      rn + wave * 1024);
        gload_lds16(wsrc + wave * 128 + 64 + lane, rn + wave * 1024 + 512);
        wsrc += 512;
        asm volatile("s_waitcnt vmcnt(2)" ::: "memory");   // current panel landed
    } else {
        asm volatile("s_waitcnt vmcnt(0)" ::: "memory");   // final panel only
    }
    asm volatile("s_barrier" ::: "memory");                // all waves' panel in
    const unsigned short* ap = rc + wave * 1024 + lane * 8;
    bf16x8 va0 = *(const bf16x8*)ap;
    bf16x8 va1 = *(const bf16x8*)(ap + 512);
    __builtin_amdgcn_s_setprio(1);
    a00 = MFMA(va0, b0, a00, 0, 0, 0);
    a10 = MFMA(va0, b1, a10, 0, 0, 0);
    a01 = MFMA(va1, b0, a01, 0, 0, 0);
    a11 = MFMA(va1, b1, a11, 0, 0, 0);
    __builtin_amdgcn_s_setprio(0);
    asm volatile("s_barrier" ::: "memory");                // reads done before rn reuse
}

// 512-out-feature layer (L1/L2): panels alternate feature halves h=0/1 at
// each k16; ring parity == h (every layer has an even panel count, so each
// layer starts at ring[0]). acc[h][bt][m], all statically indexed.
template <int K16>
__device__ __forceinline__ void layer512(
    char* act, unsigned short* ring, const uint4*& wsrc,
    const float* bias, int wave, int lane, unsigned bo0, unsigned bo1)
{
    f32x16 acc[2][2][2];
#pragma unroll
    for (int h = 0; h < 2; ++h)
#pragma unroll
      for (int b = 0; b < 2; ++b)
#pragma unroll
        for (int m = 0; m < 2; ++m)
#pragma unroll
          for (int e = 0; e < 16; ++e) acc[h][b][m][e] = 0.f;

#pragma unroll 2
    for (int k16 = 0; k16 < K16; ++k16) {
        halfstep(act, bo0, bo1, k16, ring,        ring + 4096, wsrc, true, wave, lane,
                 acc[0][0][0], acc[0][0][1], acc[0][1][0], acc[0][1][1]);
        halfstep(act, bo0, bo1, k16, ring + 4096, ring,        wsrc, true, wave, lane,
                 acc[1][0][0], acc[1][0][1], acc[1][1][0], acc[1][1][1]);
    }

    int hv = lane >> 5, lr = lane & 31;
#pragma unroll
    for (int h = 0; h < 2; ++h)
#pragma unroll
      for (int m = 0; m < 2; ++m) {
        int mt = h * 8 + wave * 2 + m;
#pragma unroll
        for (int g = 0; g < 4; ++g) {
          int f0 = mt * 32 + g * 8 + hv * 4;
          float4 bv = *(const float4*)(bias + f0);
#pragma unroll
          for (int bt = 0; bt < 2; ++bt) {
            int r = bt * 32 + lr;
            float s0 = sigmoidf(acc[h][bt][m][g * 4 + 0] + bv.x);
            float s1 = sigmoidf(acc[h][bt][m][g * 4 + 1] + bv.y);
            float s2 = sigmoidf(acc[h][bt][m][g * 4 + 2] + bv.z);
            float s3 = sigmoidf(acc[h][bt][m][g * 4 + 3] + bv.w);
            bf16x4 h4 = {(__bf16)s0, (__bf16)s1, (__bf16)s2, (__bf16)s3};
            unsigned o = (unsigned)r * 1024 + (unsigned)f0 * 2;
            *(bf16x4*)(act + swz(o)) = h4;
          }
        }
      }
    asm volatile("s_waitcnt lgkmcnt(0)" ::: "memory");     // H writes complete
    asm volatile("s_barrier" ::: "memory");                // visible to all waves
}

// 256-out-feature layer (L3): full-width panels (p = k16); pair-unrolled so
// ring parity stays static. Output -> f32 staging in act (swizzled).
template <int K16>
__device__ __forceinline__ void layer256(
    char* act, unsigned short* ring, const uint4*& wsrc,
    const float* bias, int wave, int lane, unsigned bo0, unsigned bo1)
{
    f32x16 acc[2][2];   // [bt][m]
#pragma unroll
    for (int b = 0; b < 2; ++b)
#pragma unroll
      for (int m = 0; m < 2; ++m)
#pragma unroll
        for (int e = 0; e < 16; ++e) acc[b][m][e] = 0.f;

#pragma unroll 2
    for (int kp = 0; kp < K16; kp += 2) {
        halfstep(act, bo0, bo1, kp,     ring,        ring + 4096, wsrc, true,
                 wave, lane, acc[0][0], acc[0][1], acc[1][0], acc[1][1]);
        halfstep(act, bo0, bo1, kp + 1, ring + 4096, ring,        wsrc, (kp + 2 < K16),
                 wave, lane, acc[0][0], acc[0][1], acc[1][0], acc[1][1]);
    }

    int hv = lane >> 5, lr = lane & 31;
#pragma unroll
    for (int m = 0; m < 2; ++m) {
        int mt = wave * 2 + m;
#pragma unroll
        for (int g = 0; g < 4; ++g) {
            int f0 = mt * 32 + g * 8 + hv * 4;
            float4 bv = *(const float4*)(bias + f0);
#pragma unroll
            for (int bt = 0; bt < 2; ++bt) {
                int r = bt * 32 + lr;
                float4 o4;
                o4.x = sigmoidf(acc[bt][m][g * 4 + 0] + bv.x);
                o4.y = sigmoidf(acc[bt][m][g * 4 + 1] + bv.y);
                o4.z = sigmoidf(acc[bt][m][g * 4 + 2] + bv.z);
                o4.w = sigmoidf(acc[bt][m][g * 4 + 3] + bv.w);
                unsigned o = (unsigned)r * 1024 + (unsigned)f0 * 4;
                *(float4*)(act + swz(o)) = o4;
            }
        }
    }
    asm volatile("s_waitcnt lgkmcnt(0)" ::: "memory");
    asm volatile("s_barrier" ::: "memory");
}

__global__ void __launch_bounds__(256, 2)   // 4 waves/block, 2 blocks/CU (80 KB LDS)
mlp_fused(MlpParams p, float* __restrict__ out) {
    extern __shared__ char smem[];
    char* act = smem;                                  // 64 KB, XOR-swizzled
    unsigned short* ring = (unsigned short*)(smem + 65536);  // 2 x 8 KB panels

    // bijective chunked XCD swizzle (m204): same-type blocks cluster per XCD
    int nwg = gridDim.x;
    int bid = blockIdx.x;
    int q = nwg >> 3, r8 = nwg & 7;
    int xcd = bid & 7, lid = bid >> 3;
    int b = (xcd < r8 ? xcd * (q + 1) : r8 * (q + 1) + (xcd - r8) * q) + lid;

    int t = (b >= p.blkStart[1]) + (b >= p.blkStart[2]);
    int blk = b - p.blkStart[t];
    int dIn = p.dIn[t];
    int Nt = p.Nt[t];
    int row0 = blk * BM;
    const float* X = p.X[t];
    const uint4* wsrc = (const uint4*)p.Wp[t];

    int tid = threadIdx.x;
    int wave = tid >> 6;
    int lane = tid & 63;

    // prologue: panel 0 of the continuous (L1|L2|L3) panel stream
    gload_lds16(wsrc + wave * 128 + lane,      ring + wave * 1024);
    gload_lds16(wsrc + wave * 128 + 64 + lane, ring + wave * 1024 + 512);
    wsrc += 512;

    // ---- stage X (fp32 global -> bf16 swizzled LDS rows [64][feat]) ----
    int d4 = dIn >> 2;               // float4 per row (16/32/64)
    int s4 = 31 - __clz(d4);
    int nf4 = BM * d4;
    for (int i = tid; i < nf4; i += 256) {
        int r = i >> s4;
        int c4 = i & (d4 - 1);
        int grow = row0 + r;
        float4 v = make_float4(0.f, 0.f, 0.f, 0.f);
        if (grow < Nt) v = ((const float4*)X)[(size_t)grow * d4 + c4];
        ushort4 u;
        u.x = __builtin_bit_cast(unsigned short, (__bf16)v.x);
        u.y = __builtin_bit_cast(unsigned short, (__bf16)v.y);
        u.z = __builtin_bit_cast(unsigned short, (__bf16)v.z);
        u.w = __builtin_bit_cast(unsigned short, (__bf16)v.w);
        unsigned o = (unsigned)r * 1024 + (unsigned)c4 * 8;
        *(ushort4*)(act + swz(o)) = u;
    }
    __syncthreads();   // X staged + panel 0 landed (full drain, once)

    unsigned bo0 = (unsigned)(lane & 31) * 1024 + (unsigned)(lane >> 5) * 16;
    unsigned bo1 = bo0 + 32 * 1024;

    if (t == 0)      layer512<4 >(act, ring, wsrc, p.B1[0], wave, lane, bo0, bo1);
    else if (t == 1) layer512<8 >(act, ring, wsrc, p.B1[1], wave, lane, bo0, bo1);
    else             layer512<16>(act, ring, wsrc, p.B1[2], wave, lane, bo0, bo1);
    layer512<32>(act, ring, wsrc, p.B2[t], wave, lane, bo0, bo1);
    layer256<32>(act, ring, wsrc, p.B3[t], wave, lane, bo0, bo1);

    // ---- coalesced output store: 64 rows x 256 f32 from swizzled staging ----
    float* gOut = out + (size_t)(p.rowOff[t] + row0) * 256;
    for (int i = tid; i < BM * 64; i += 256) {   // 4096 float4
        int r = i >> 6;
        int c4 = i & 63;
        if (row0 + r < Nt) {
            unsigned o = (unsigned)r * 1024 + (unsigned)c4 * 16;
            *(float4*)(gOut + r * 256 + c4 * 4) = *(const float4*)(act + swz(o));
        }
    }
}

// ---------------- launch ----------------
extern "C" void kernel_launch(void* const* d_in, const int* in_sizes, int n_in,
                              void* d_out, int out_size, void* d_ws, size_t ws_size,
                              hipStream_t stream) {
    const int IN0[3] = {64, 128, 256};
    const int CNT[3] = {100000, 80000, 60000};

    // ---- prepack weights into ws (bf16, panel-major A-fragment order) ----
    PrepParams pp;
    int blocks = 0, ubase = 0;
    for (int t = 0; t < 3; ++t) {
        int Ks[3] = {IN0[t], 512, 512};
        int Ns[3] = {512, 512, 256};
        for (int l = 0; l < 3; ++l) {
            int w = t * 3 + l;
            pp.src[w] = (const float*)d_in[4 + t * 6 + l * 2];
            pp.Kt[w] = Ks[l] >> 5;
            pp.Mg[w] = Ns[l] >> 7;
            pp.N[w] = Ns[l];
            pp.unitBase[w] = ubase;
            blocks += pp.Kt[w] * pp.Mg[w];
            pp.blkEnd[w] = blocks;
            ubase += (Ks[l] * Ns[l]) >> 3;
        }
    }
    prep_weights<<<dim3(blocks), dim3(256), 0, stream>>>(pp, (uint4*)d_ws);

    // ---- fused MLP ----
    MlpParams mp;
    int woff = 0, roff = 0, boff = 0;
    for (int t = 0; t < 3; ++t) {
        mp.X[t] = (const float*)d_in[t];
        mp.Wp[t] = (const unsigned short*)d_ws + woff;
        mp.B1[t] = (const float*)d_in[4 + t * 6 + 1];
        mp.B2[t] = (const float*)d_in[4 + t * 6 + 3];
        mp.B3[t] = (const float*)d_in[4 + t * 6 + 5];
        mp.dIn[t] = IN0[t];
        mp.Nt[t] = CNT[t];
        mp.rowOff[t] = roff;
        mp.blkStart[t] = boff;
        woff += IN0[t] * 512 + 512 * 512 + 512 * 256;
        roff += CNT[t];
        boff += (CNT[t] + BM - 1) / BM;
    }
    size_t lds = 65536 + 2 * 8192;   // act 64 KB + panel ring 16 KB = 80 KB
    mlp_fused<<<dim3(boff), dim3(256), lds, stream>>>(mp, (float*)d_out);
}